// Round 2
// baseline (2262.358 us; speedup 1.0000x reference)
//
#include <hip/hip_runtime.h>
#include <math.h>

#define B_ 4
#define T_ 2048
#define C_ 2048
#define H_ 16
#define HD_ 128

typedef __attribute__((ext_vector_type(8))) short short8;
typedef __attribute__((ext_vector_type(4))) float f32x4;
typedef unsigned short u16;

__device__ __forceinline__ u16 f2bf(float f) {
  union { float f; unsigned u; } v; v.f = f;
  unsigned r = v.u + 0x7FFFu + ((v.u >> 16) & 1u);
  return (u16)(r >> 16);
}

__device__ __forceinline__ void gld16(const void* g, void* l) {
  __builtin_amdgcn_global_load_lds(
      (__attribute__((address_space(1))) void*)(void*)g,
      (__attribute__((address_space(3))) void*)l, 16, 0, 0);
}

// ---------------- transpose fp32 (K x N) -> bf16 (N x K) ----------------
__global__ __launch_bounds__(256) void tconv(const float* __restrict__ in,
                                             u16* __restrict__ out,
                                             int K, int N,
                                             long inBS, long outBS) {
  __shared__ float tile[32][33];
  const float* inb = in + (long)blockIdx.z * inBS;
  u16* outb = out + (long)blockIdx.z * outBS;
  int k0 = blockIdx.x << 5, n0 = blockIdx.y << 5;
  int t = threadIdx.x;
  {
    int kk = t >> 3, nn = (t & 7) << 2;
    float4 v = *(const float4*)(inb + (long)(k0 + kk) * N + n0 + nn);
    tile[kk][nn + 0] = v.x; tile[kk][nn + 1] = v.y;
    tile[kk][nn + 2] = v.z; tile[kk][nn + 3] = v.w;
  }
  __syncthreads();
  {
    int nn = t >> 3, kk = (t & 7) << 2;
    ushort4 o;
    o.x = f2bf(tile[kk + 0][nn]); o.y = f2bf(tile[kk + 1][nn]);
    o.z = f2bf(tile[kk + 2][nn]); o.w = f2bf(tile[kk + 3][nn]);
    *(ushort4*)(outb + (long)(n0 + nn) * K + k0 + kk) = o;
  }
}

// ---------------- LayerNorm row kernel: fp32 in -> bf16 out ----------------
__global__ __launch_bounds__(256) void ln_rows(const float* __restrict__ x,
                                               const float* __restrict__ gam,
                                               const float* __restrict__ bet,
                                               u16* __restrict__ out) {
  int row = blockIdx.x;
  const float* xr = x + (size_t)row * C_;
  int t = threadIdx.x;
  float4 v0 = *(const float4*)(xr + t * 8);
  float4 v1 = *(const float4*)(xr + t * 8 + 4);
  float s = v0.x + v0.y + v0.z + v0.w + v1.x + v1.y + v1.z + v1.w;
  float ss = v0.x * v0.x + v0.y * v0.y + v0.z * v0.z + v0.w * v0.w +
             v1.x * v1.x + v1.y * v1.y + v1.z * v1.z + v1.w * v1.w;
  for (int d = 32; d > 0; d >>= 1) {
    s += __shfl_down(s, d);
    ss += __shfl_down(ss, d);
  }
  __shared__ float red[8];
  int wv = t >> 6;
  if ((t & 63) == 0) { red[wv] = s; red[4 + wv] = ss; }
  __syncthreads();
  s = red[0] + red[1] + red[2] + red[3];
  ss = red[4] + red[5] + red[6] + red[7];
  float mu = s * (1.0f / C_);
  float var = ss * (1.0f / C_) - mu * mu;
  float rs = rsqrtf(var + 1e-5f);
  int c = t * 8;
  float vv[8] = {v0.x, v0.y, v0.z, v0.w, v1.x, v1.y, v1.z, v1.w};
  ushort4 o0, o1;
  o0.x = f2bf((vv[0] - mu) * rs * gam[c + 0] + bet[c + 0]);
  o0.y = f2bf((vv[1] - mu) * rs * gam[c + 1] + bet[c + 1]);
  o0.z = f2bf((vv[2] - mu) * rs * gam[c + 2] + bet[c + 2]);
  o0.w = f2bf((vv[3] - mu) * rs * gam[c + 3] + bet[c + 3]);
  o1.x = f2bf((vv[4] - mu) * rs * gam[c + 4] + bet[c + 4]);
  o1.y = f2bf((vv[5] - mu) * rs * gam[c + 5] + bet[c + 5]);
  o1.z = f2bf((vv[6] - mu) * rs * gam[c + 6] + bet[c + 6]);
  o1.w = f2bf((vv[7] - mu) * rs * gam[c + 7] + bet[c + 7]);
  *(ushort4*)(out + (size_t)row * C_ + c) = o0;
  *(ushort4*)(out + (size_t)row * C_ + c + 4) = o1;
}

// ---------------- bf16 GEMM: C = A(MxK) * BT(NxK)^T, epilogue variants ----------------
template <int EPI>
__global__ __launch_bounds__(256) void gemm_bt(
    const u16* __restrict__ A, const u16* __restrict__ BT,
    int M, int N, int K, int lda, int ldb,
    u16* __restrict__ oq, u16* __restrict__ ok, u16* __restrict__ ovt,
    float* __restrict__ of32, const float* __restrict__ resid,
    const float* __restrict__ bias, u16* __restrict__ obf, int addBias) {
  __shared__ u16 As[128 * 32];
  __shared__ u16 Bs[128 * 32];
  int nbx = N >> 7;
  int nwg = gridDim.x;
  int flat = blockIdx.x;
  int sw = (flat & 7) * (nwg >> 3) + (flat >> 3);  // nwg % 8 == 0 for all uses
  int bx = sw % nbx, by = sw / nbx;
  int m0 = by << 7, n0 = bx << 7;
  int tid = threadIdx.x;
  int lane = tid & 63, wave = tid >> 6;
  int wr = wave >> 1, wc = wave & 1;
  int l15 = lane & 15, l16 = lane >> 4;

  f32x4 acc[4][4] = {};
  const char* Ab = (const char*)A;
  const char* Bb = (const char*)BT;
  int off0 = wave * 1024 + lane * 16;

  for (int k0 = 0; k0 < K; k0 += 32) {
#pragma unroll
    for (int it = 0; it < 2; ++it) {
      int off = off0 + it * 4096;
      int row = off >> 6, kb = off & 63;
      gld16(Ab + ((long)(m0 + row) * lda + k0) * 2 + kb, (char*)As + off);
      gld16(Bb + ((long)(n0 + row) * ldb + k0) * 2 + kb, (char*)Bs + off);
    }
    __syncthreads();
    short8 af[4], bfr[4];
#pragma unroll
    for (int i = 0; i < 4; ++i) {
      af[i] = *(const short8*)(As + (wr * 64 + i * 16 + l15) * 32 + l16 * 8);
      bfr[i] = *(const short8*)(Bs + (wc * 64 + i * 16 + l15) * 32 + l16 * 8);
    }
#pragma unroll
    for (int mi = 0; mi < 4; ++mi)
#pragma unroll
      for (int nj = 0; nj < 4; ++nj)
        acc[mi][nj] = __builtin_amdgcn_mfma_f32_16x16x32_bf16(af[mi], bfr[nj],
                                                              acc[mi][nj], 0, 0, 0);
    __syncthreads();
  }

  int rowb = m0 + wr * 64 + l16 * 4;
  int colb = n0 + wc * 64 + l15;
#pragma unroll
  for (int mi = 0; mi < 4; ++mi) {
#pragma unroll
    for (int nj = 0; nj < 4; ++nj) {
      int col = colb + nj * 16;
      if constexpr (EPI == 0) {
        int seg = col >> 11, cn = col & 2047;
        int hh = cn >> 7, dd = cn & 127;
        int row0 = rowb + mi * 16;
        int bb = row0 >> 11, t0 = row0 & 2047;
        if (seg == 2) {
          ushort4 o;
          o.x = f2bf(acc[mi][nj][0]); o.y = f2bf(acc[mi][nj][1]);
          o.z = f2bf(acc[mi][nj][2]); o.w = f2bf(acc[mi][nj][3]);
          *(ushort4*)(ovt + ((long)(bb * H_ + hh) * HD_ + dd) * T_ + t0) = o;
        } else {
          u16* dst = (seg == 0) ? oq : ok;
#pragma unroll
          for (int r = 0; r < 4; ++r)
            dst[((long)(bb * H_ + hh) * T_ + t0 + r) * HD_ + dd] =
                f2bf(acc[mi][nj][r]);
        }
      } else if constexpr (EPI == 1) {
#pragma unroll
        for (int r = 0; r < 4; ++r) {
          long idx = (long)(rowb + mi * 16 + r) * N + col;
          of32[idx] = resid[idx] + bias[col] + acc[mi][nj][r];
        }
      } else if constexpr (EPI == 2) {
#pragma unroll
        for (int r = 0; r < 4; ++r) {
          float v = acc[mi][nj][r] + bias[col];
          float g = 0.5f * v * (1.0f + erff(v * 0.70710678118654752f));
          obf[(long)(rowb + mi * 16 + r) * N + col] = f2bf(g);
        }
      } else {
#pragma unroll
        for (int r = 0; r < 4; ++r) {
          long idx = (long)(rowb + mi * 16 + r) * N + col;
          float v = acc[mi][nj][r];
          if (addBias) v += bias[col];
          of32[idx] += v;
        }
      }
    }
  }
}

// ---------------- flash attention (causal), bf16, D=128 ----------------
// grid: (T/128, B*H). 4 waves, each owns 32 Q rows. KV tile = 64.
// All LDS tiles XOR-swizzled (slot ^= row&7); K/V staged via global_load_lds
// with pre-swizzled per-lane GLOBAL source (LDS dest stays linear).
__global__ __launch_bounds__(256) void attn_fwd(const u16* __restrict__ q,
                                                const u16* __restrict__ k,
                                                const u16* __restrict__ vt,
                                                u16* __restrict__ o) {
  __shared__ u16 Ks[64 * 128];    // [s][d], 256B rows, swizzled
  __shared__ u16 Vs[128 * 64];    // [d][s], 128B rows, swizzled
  __shared__ u16 Ps[4][32 * 64];  // per-wave P [t][s], 128B rows, swizzled
  int q0 = blockIdx.x << 7, bh = blockIdx.y;
  int tid = threadIdx.x, lane = tid & 63, wave = tid >> 6;
  int l15 = lane & 15, l16 = lane >> 4;
  int wq0 = q0 + wave * 32;

  // Q fragments in registers: rows wq0 + rf*16 + l15, k = kk*32 + l16*8
  short8 qf[2][4];
#pragma unroll
  for (int rf = 0; rf < 2; ++rf)
#pragma unroll
    for (int kk = 0; kk < 4; ++kk)
      qf[rf][kk] = *(const short8*)(q + ((long)bh * T_ + wq0 + rf * 16 + l15) * HD_ +
                                    kk * 32 + l16 * 8);

  f32x4 accO[2][8] = {};
  float m_r[2][4], l_r[2][4];
#pragma unroll
  for (int rf = 0; rf < 2; ++rf)
#pragma unroll
    for (int r = 0; r < 4; ++r) { m_r[rf][r] = -INFINITY; l_r[rf][r] = 0.f; }
  const float sc = 0.08838834764831845f * 1.4426950408889634f;  // rsqrt(128)*log2e

  int send = q0 + 128;
  for (int s0 = 0; s0 < send; s0 += 64) {
    __syncthreads();
#pragma unroll
    for (int it = 0; it < 4; ++it) {
      int off = wave * 4096 + it * 1024 + lane * 16;
      // K: row s = off>>8 (256B rows, 16 slots); source slot pre-swizzled
      int krow = off >> 8;
      int kslot = (lane & 15) ^ (krow & 7);
      gld16(k + ((long)(bh * T_ + s0 + krow)) * HD_ + kslot * 8, (char*)Ks + off);
      // V: row d = off>>7 (128B rows, 8 slots)
      int dd = off >> 7;
      int vslot = (lane & 7) ^ (dd & 7);
      gld16(vt + ((long)(bh * HD_ + dd)) * T_ + s0 + vslot * 8, (char*)Vs + off);
    }
    __syncthreads();
    if (s0 <= wq0 + 31) {  // wave-uniform: tile intersects this wave's rows
      bool needmask = (s0 + 63 > wq0);
#pragma unroll
      for (int rf = 0; rf < 2; ++rf) {
        f32x4 S[4];
#pragma unroll
        for (int sb = 0; sb < 4; ++sb) {
          f32x4 s = {};
#pragma unroll
          for (int kk = 0; kk < 4; ++kk) {
            int srow = sb * 16 + l15;
            int kb = srow * 256 + (((kk * 4 + l16) ^ (srow & 7)) << 4);
            short8 kf = *(const short8*)((const char*)Ks + kb);
            s = __builtin_amdgcn_mfma_f32_16x16x32_bf16(qf[rf][kk], kf, s, 0, 0, 0);
          }
          S[sb] = s;
        }
        float al[4];
#pragma unroll
        for (int r = 0; r < 4; ++r) {
          int tt = wq0 + rf * 16 + 4 * l16 + r;
          float v[4];
#pragma unroll
          for (int sb = 0; sb < 4; ++sb) {
            v[sb] = S[sb][r] * sc;
            if (needmask && (s0 + sb * 16 + l15 > tt)) v[sb] = -INFINITY;
          }
          float mx = fmaxf(fmaxf(v[0], v[1]), fmaxf(v[2], v[3]));
          mx = fmaxf(mx, __shfl_xor(mx, 1));
          mx = fmaxf(mx, __shfl_xor(mx, 2));
          mx = fmaxf(mx, __shfl_xor(mx, 4));
          mx = fmaxf(mx, __shfl_xor(mx, 8));
          float mn = fmaxf(m_r[rf][r], mx);
          al[r] = exp2f(m_r[rf][r] - mn);
          m_r[rf][r] = mn;
          int prow = rf * 16 + 4 * l16 + r;
          float rs = 0.f;
#pragma unroll
          for (int sb = 0; sb < 4; ++sb) {
            float p = exp2f(v[sb] - mn);
            rs += p;
            int col = sb * 16 + l15;
            int pb = (prow * 128 + col * 2) ^ ((prow & 7) << 4);
            *(u16*)((char*)Ps[wave] + pb) = f2bf(p);
          }
          rs += __shfl_xor(rs, 1);
          rs += __shfl_xor(rs, 2);
          rs += __shfl_xor(rs, 4);
          rs += __shfl_xor(rs, 8);
          l_r[rf][r] = l_r[rf][r] * al[r] + rs;
        }
#pragma unroll
        for (int db = 0; db < 8; ++db)
#pragma unroll
          for (int r = 0; r < 4; ++r) accO[rf][db][r] *= al[r];
        short8 pf[2];
#pragma unroll
        for (int st = 0; st < 2; ++st) {
          int prow = rf * 16 + l15;
          int pb = (prow * 128 + (st * 4 + l16) * 16) ^ ((prow & 7) << 4);
          pf[st] = *(const short8*)((const char*)Ps[wave] + pb);
        }
#pragma unroll
        for (int db = 0; db < 8; ++db) {
#pragma unroll
          for (int st = 0; st < 2; ++st) {
            int vrow = db * 16 + l15;
            int vb = (vrow * 128 + (st * 4 + l16) * 16) ^ ((vrow & 7) << 4);
            short8 vf = *(const short8*)((const char*)Vs + vb);
            accO[rf][db] = __builtin_amdgcn_mfma_f32_16x16x32_bf16(pf[st], vf,
                                                                   accO[rf][db], 0, 0, 0);
          }
        }
      }
    }
  }
  int bb = bh >> 4, hh = bh & 15;
#pragma unroll
  for (int rf = 0; rf < 2; ++rf) {
    float inv[4];
#pragma unroll
    for (int r = 0; r < 4; ++r) inv[r] = 1.0f / l_r[rf][r];
#pragma unroll
    for (int db = 0; db < 8; ++db)
#pragma unroll
      for (int r = 0; r < 4; ++r) {
        int tt = wq0 + rf * 16 + 4 * l16 + r;
        o[((long)bb * T_ + tt) * C_ + hh * HD_ + db * 16 + l15] =
            f2bf(accO[rf][db][r] * inv[r]);
      }
  }
}

extern "C" void kernel_launch(void* const* d_in, const int* in_sizes, int n_in,
                              void* d_out, int out_size, void* d_ws, size_t ws_size,
                              hipStream_t stream) {
  (void)in_sizes; (void)n_in; (void)out_size; (void)ws_size;
  const float* x   = (const float*)d_in[0];
  const float* Wq  = (const float*)d_in[1];
  const float* Wk  = (const float*)d_in[2];
  const float* Wv  = (const float*)d_in[3];
  const float* Wp  = (const float*)d_in[4];
  const float* bp  = (const float*)d_in[5];
  const float* W1  = (const float*)d_in[6];
  const float* b1  = (const float*)d_in[7];
  const float* W2  = (const float*)d_in[8];
  const float* b2  = (const float*)d_in[9];
  const float* g1  = (const float*)d_in[10];
  const float* be1 = (const float*)d_in[11];
  const float* g2  = (const float*)d_in[12];
  const float* be2 = (const float*)d_in[13];
  float* out = (float*)d_out;

  char* ws = (char*)d_ws;
  size_t off = 0;
  auto alloc = [&](size_t n) {
    void* p = ws + off;
    off += (n + 255) & ~(size_t)255;
    return p;
  };
  u16* wqkvT = (u16*)alloc((size_t)6144 * 2048 * 2);
  u16* wpT   = (u16*)alloc((size_t)2048 * 2048 * 2);
  u16* w1T   = (u16*)alloc((size_t)8192 * 2048 * 2);
  u16* w2T   = (u16*)alloc((size_t)2048 * 8192 * 2);
  u16* hb    = (u16*)alloc((size_t)8192 * 2048 * 2);
  u16* qbuf  = (u16*)alloc((size_t)8192 * 2048 * 2);
  u16* kbuf  = (u16*)alloc((size_t)8192 * 2048 * 2);
  u16* vtbuf = (u16*)alloc((size_t)8192 * 2048 * 2);
  u16* ob = hb;
  u16* fb = qbuf;

  tconv<<<dim3(64, 4, 16), 256, 0, stream>>>(Wq, wqkvT, 2048, 128,
                                             (long)2048 * 128, (long)128 * 2048);
  tconv<<<dim3(64, 4, 16), 256, 0, stream>>>(Wk, wqkvT + (size_t)2048 * 2048, 2048, 128,
                                             (long)2048 * 128, (long)128 * 2048);
  tconv<<<dim3(64, 4, 16), 256, 0, stream>>>(Wv, wqkvT + (size_t)4096 * 2048, 2048, 128,
                                             (long)2048 * 128, (long)128 * 2048);
  tconv<<<dim3(64, 64, 1), 256, 0, stream>>>(Wp, wpT, 2048, 2048, 0, 0);
  tconv<<<dim3(64, 256, 1), 256, 0, stream>>>(W1, w1T, 2048, 8192, 0, 0);
  tconv<<<dim3(256, 64, 1), 256, 0, stream>>>(W2, w2T, 8192, 2048, 0, 0);

  ln_rows<<<8192, 256, 0, stream>>>(x, g1, be1, hb);
  gemm_bt<0><<<3072, 256, 0, stream>>>(hb, wqkvT, 8192, 6144, 2048, 2048, 2048,
                                       qbuf, kbuf, vtbuf, nullptr, nullptr,
                                       nullptr, nullptr, 0);
  attn_fwd<<<dim3(16, 64), 256, 0, stream>>>(qbuf, kbuf, vtbuf, ob);
  gemm_bt<1><<<1024, 256, 0, stream>>>(ob, wpT, 8192, 2048, 2048, 2048, 2048,
                                       nullptr, nullptr, nullptr, out, x, bp,
                                       nullptr, 0);

  ln_rows<<<8192, 256, 0, stream>>>(out, g2, be2, hb);
  for (int c = 0; c < 4; ++c) {
    gemm_bt<2><<<1024, 256, 0, stream>>>(hb, w1T + (size_t)c * 2048 * 2048,
                                         8192, 2048, 2048, 2048, 2048,
                                         nullptr, nullptr, nullptr, nullptr,
                                         nullptr, b1 + c * 2048, fb, 0);
    gemm_bt<3><<<1024, 256, 0, stream>>>(fb, w2T + (size_t)c * 2048,
                                         8192, 2048, 2048, 2048, 8192,
                                         nullptr, nullptr, nullptr, out,
                                         nullptr, b2, nullptr, c == 0 ? 1 : 0);
  }
}

// Round 3
// 2027.791 us; speedup vs baseline: 1.1157x; 1.1157x over previous
//
#include <hip/hip_runtime.h>
#include <math.h>

#define B_ 4
#define T_ 2048
#define C_ 2048
#define H_ 16
#define HD_ 128

typedef __attribute__((ext_vector_type(8))) short short8;
typedef __attribute__((ext_vector_type(4))) float f32x4;
typedef unsigned short u16;

__device__ __forceinline__ u16 f2bf(float f) {
  union { float f; unsigned u; } v; v.f = f;
  unsigned r = v.u + 0x7FFFu + ((v.u >> 16) & 1u);
  return (u16)(r >> 16);
}

__device__ __forceinline__ void gld16(const void* g, void* l) {
  __builtin_amdgcn_global_load_lds(
      (__attribute__((address_space(1))) void*)(void*)g,
      (__attribute__((address_space(3))) void*)l, 16, 0, 0);
}

// ---------------- transpose fp32 (K x N) -> bf16 (N x K) ----------------
__global__ __launch_bounds__(256) void tconv(const float* __restrict__ in,
                                             u16* __restrict__ out,
                                             int K, int N,
                                             long inBS, long outBS) {
  __shared__ float tile[32][33];
  const float* inb = in + (long)blockIdx.z * inBS;
  u16* outb = out + (long)blockIdx.z * outBS;
  int k0 = blockIdx.x << 5, n0 = blockIdx.y << 5;
  int t = threadIdx.x;
  {
    int kk = t >> 3, nn = (t & 7) << 2;
    float4 v = *(const float4*)(inb + (long)(k0 + kk) * N + n0 + nn);
    tile[kk][nn + 0] = v.x; tile[kk][nn + 1] = v.y;
    tile[kk][nn + 2] = v.z; tile[kk][nn + 3] = v.w;
  }
  __syncthreads();
  {
    int nn = t >> 3, kk = (t & 7) << 2;
    ushort4 o;
    o.x = f2bf(tile[kk + 0][nn]); o.y = f2bf(tile[kk + 1][nn]);
    o.z = f2bf(tile[kk + 2][nn]); o.w = f2bf(tile[kk + 3][nn]);
    *(ushort4*)(outb + (long)(n0 + nn) * K + k0 + kk) = o;
  }
}

// ---------------- LayerNorm row kernel: fp32 in -> bf16 out ----------------
__global__ __launch_bounds__(256) void ln_rows(const float* __restrict__ x,
                                               const float* __restrict__ gam,
                                               const float* __restrict__ bet,
                                               u16* __restrict__ out) {
  int row = blockIdx.x;
  const float* xr = x + (size_t)row * C_;
  int t = threadIdx.x;
  float4 v0 = *(const float4*)(xr + t * 8);
  float4 v1 = *(const float4*)(xr + t * 8 + 4);
  float s = v0.x + v0.y + v0.z + v0.w + v1.x + v1.y + v1.z + v1.w;
  float ss = v0.x * v0.x + v0.y * v0.y + v0.z * v0.z + v0.w * v0.w +
             v1.x * v1.x + v1.y * v1.y + v1.z * v1.z + v1.w * v1.w;
  for (int d = 32; d > 0; d >>= 1) {
    s += __shfl_down(s, d);
    ss += __shfl_down(ss, d);
  }
  __shared__ float red[8];
  int wv = t >> 6;
  if ((t & 63) == 0) { red[wv] = s; red[4 + wv] = ss; }
  __syncthreads();
  s = red[0] + red[1] + red[2] + red[3];
  ss = red[4] + red[5] + red[6] + red[7];
  float mu = s * (1.0f / C_);
  float var = ss * (1.0f / C_) - mu * mu;
  float rs = rsqrtf(var + 1e-5f);
  int c = t * 8;
  float vv[8] = {v0.x, v0.y, v0.z, v0.w, v1.x, v1.y, v1.z, v1.w};
  ushort4 o0, o1;
  o0.x = f2bf((vv[0] - mu) * rs * gam[c + 0] + bet[c + 0]);
  o0.y = f2bf((vv[1] - mu) * rs * gam[c + 1] + bet[c + 1]);
  o0.z = f2bf((vv[2] - mu) * rs * gam[c + 2] + bet[c + 2]);
  o0.w = f2bf((vv[3] - mu) * rs * gam[c + 3] + bet[c + 3]);
  o1.x = f2bf((vv[4] - mu) * rs * gam[c + 4] + bet[c + 4]);
  o1.y = f2bf((vv[5] - mu) * rs * gam[c + 5] + bet[c + 5]);
  o1.z = f2bf((vv[6] - mu) * rs * gam[c + 6] + bet[c + 6]);
  o1.w = f2bf((vv[7] - mu) * rs * gam[c + 7] + bet[c + 7]);
  *(ushort4*)(out + (size_t)row * C_ + c) = o0;
  *(ushort4*)(out + (size_t)row * C_ + c + 4) = o1;
}

// ---------------- bf16 GEMM: C = A(MxK) * BT(NxK)^T, epilogue variants ----------------
template <int EPI>
__global__ __launch_bounds__(256) void gemm_bt(
    const u16* __restrict__ A, const u16* __restrict__ BT,
    int M, int N, int K, int lda, int ldb,
    u16* __restrict__ oq, u16* __restrict__ ok, u16* __restrict__ ovt,
    float* __restrict__ of32, const float* __restrict__ resid,
    const float* __restrict__ bias, u16* __restrict__ obf, int addBias) {
  __shared__ u16 As[128 * 32];
  __shared__ u16 Bs[128 * 32];
  int nbx = N >> 7;
  int nwg = gridDim.x;
  int flat = blockIdx.x;
  int sw = (flat & 7) * (nwg >> 3) + (flat >> 3);  // nwg % 8 == 0 for all uses
  int bx = sw % nbx, by = sw / nbx;
  int m0 = by << 7, n0 = bx << 7;
  int tid = threadIdx.x;
  int lane = tid & 63, wave = tid >> 6;
  int wr = wave >> 1, wc = wave & 1;
  int l15 = lane & 15, l16 = lane >> 4;

  f32x4 acc[4][4] = {};
  const char* Ab = (const char*)A;
  const char* Bb = (const char*)BT;
  int off0 = wave * 1024 + lane * 16;

  for (int k0 = 0; k0 < K; k0 += 32) {
#pragma unroll
    for (int it = 0; it < 2; ++it) {
      int off = off0 + it * 4096;
      int row = off >> 6, kb = off & 63;
      gld16(Ab + ((long)(m0 + row) * lda + k0) * 2 + kb, (char*)As + off);
      gld16(Bb + ((long)(n0 + row) * ldb + k0) * 2 + kb, (char*)Bs + off);
    }
    __syncthreads();
    short8 af[4], bfr[4];
#pragma unroll
    for (int i = 0; i < 4; ++i) {
      af[i] = *(const short8*)(As + (wr * 64 + i * 16 + l15) * 32 + l16 * 8);
      bfr[i] = *(const short8*)(Bs + (wc * 64 + i * 16 + l15) * 32 + l16 * 8);
    }
#pragma unroll
    for (int mi = 0; mi < 4; ++mi)
#pragma unroll
      for (int nj = 0; nj < 4; ++nj)
        acc[mi][nj] = __builtin_amdgcn_mfma_f32_16x16x32_bf16(af[mi], bfr[nj],
                                                              acc[mi][nj], 0, 0, 0);
    __syncthreads();
  }

  int rowb = m0 + wr * 64 + l16 * 4;
  int colb = n0 + wc * 64 + l15;
#pragma unroll
  for (int mi = 0; mi < 4; ++mi) {
#pragma unroll
    for (int nj = 0; nj < 4; ++nj) {
      int col = colb + nj * 16;
      if constexpr (EPI == 0) {
        int seg = col >> 11, cn = col & 2047;
        int hh = cn >> 7, dd = cn & 127;
        int row0 = rowb + mi * 16;
        int bb = row0 >> 11, t0 = row0 & 2047;
        if (seg == 2) {
          ushort4 o;
          o.x = f2bf(acc[mi][nj][0]); o.y = f2bf(acc[mi][nj][1]);
          o.z = f2bf(acc[mi][nj][2]); o.w = f2bf(acc[mi][nj][3]);
          *(ushort4*)(ovt + ((long)(bb * H_ + hh) * HD_ + dd) * T_ + t0) = o;
        } else {
          u16* dst = (seg == 0) ? oq : ok;
#pragma unroll
          for (int r = 0; r < 4; ++r)
            dst[((long)(bb * H_ + hh) * T_ + t0 + r) * HD_ + dd] =
                f2bf(acc[mi][nj][r]);
        }
      } else if constexpr (EPI == 1) {
#pragma unroll
        for (int r = 0; r < 4; ++r) {
          long idx = (long)(rowb + mi * 16 + r) * N + col;
          of32[idx] = resid[idx] + bias[col] + acc[mi][nj][r];
        }
      } else if constexpr (EPI == 2) {
#pragma unroll
        for (int r = 0; r < 4; ++r) {
          float v = acc[mi][nj][r] + bias[col];
          float g = 0.5f * v * (1.0f + erff(v * 0.70710678118654752f));
          obf[(long)(rowb + mi * 16 + r) * N + col] = f2bf(g);
        }
      } else {
#pragma unroll
        for (int r = 0; r < 4; ++r) {
          long idx = (long)(rowb + mi * 16 + r) * N + col;
          float v = acc[mi][nj][r];
          if (addBias) v += bias[col];
          of32[idx] += v;
        }
      }
    }
  }
}

// ---------------- flash attention (causal), bf16, D=128 ----------------
// 1D grid 1024, heavy-first: qb = 15 - bid/64, bh = bid&63. QBLK=128 (4 waves
// x 32 rows), KVBLK=64. Single-buffer K/V in LDS (48KB -> 3 blocks/CU) with
// T14 async-STAGE: next tile global->regs at loop top (latency hides under
// compute), swizzled ds_write after the read barrier. Defer-max (THR=8).
__global__ __launch_bounds__(256) void attn_fwd(const u16* __restrict__ q,
                                                const u16* __restrict__ k,
                                                const u16* __restrict__ vt,
                                                u16* __restrict__ o) {
  __shared__ u16 Ks[64 * 128];    // [s][d], 256B rows, XOR-swizzled slots
  __shared__ u16 Vs[128 * 64];    // [d][s], 128B rows, XOR-swizzled slots
  __shared__ u16 Ps[4][32 * 64];  // per-wave P [t][s], swizzled
  int bid = blockIdx.x;
  int bh = bid & 63;
  int qb = 15 - (bid >> 6);
  int q0 = qb << 7;
  int tid = threadIdx.x, lane = tid & 63, wave = tid >> 6;
  int l15 = lane & 15, l16 = lane >> 4;
  int wq0 = q0 + wave * 32;

  short8 qf[2][4];
#pragma unroll
  for (int rf = 0; rf < 2; ++rf)
#pragma unroll
    for (int kk = 0; kk < 4; ++kk)
      qf[rf][kk] = *(const short8*)(q + ((long)bh * T_ + wq0 + rf * 16 + l15) * HD_ +
                                    kk * 32 + l16 * 8);

  f32x4 accO[2][8] = {};
  float m_r[2][4], l_r[2][4];
#pragma unroll
  for (int rf = 0; rf < 2; ++rf)
#pragma unroll
    for (int r = 0; r < 4; ++r) { m_r[rf][r] = -INFINITY; l_r[rf][r] = 0.f; }
  const float sc = 0.08838834764831845f * 1.4426950408889634f;  // rsqrt(128)*log2e

  int nt = (q0 >> 6) + 2;  // tiles of 64 KV rows
  int off0 = wave * 4096 + lane * 16;

  int4 kreg[4], vreg[4];
  auto regload = [&](int t) {
    int s0 = t << 6;
#pragma unroll
    for (int it = 0; it < 4; ++it) {
      int off = off0 + it * 1024;
      int krow = off >> 8;
      kreg[it] = *(const int4*)((const char*)(k + ((long)bh * T_ + s0 + krow) * HD_) +
                                (off & 255));
      int dd = off >> 7;
      vreg[it] = *(const int4*)((const char*)(vt + ((long)bh * HD_ + dd) * T_ + s0) +
                                (off & 127));
    }
  };
  auto dswrite = [&]() {
#pragma unroll
    for (int it = 0; it < 4; ++it) {
      int off = off0 + it * 1024;
      int krow = off >> 8;
      *(int4*)((char*)Ks + (off ^ ((krow & 7) << 4))) = kreg[it];
      int dd = off >> 7;
      *(int4*)((char*)Vs + (off ^ ((dd & 7) << 4))) = vreg[it];
    }
  };

  regload(0);
  dswrite();
  __syncthreads();

  for (int t = 0; t < nt; ++t) {
    int s0 = t << 6;
    bool more = (t + 1 < nt);
    if (more) regload(t + 1);  // issue early: HBM latency hides under compute

    if (s0 <= wq0 + 31) {  // wave-uniform causal skip
      bool needmask = (s0 + 63 > wq0);
#pragma unroll
      for (int rf = 0; rf < 2; ++rf) {
        f32x4 S[4];
#pragma unroll
        for (int sb = 0; sb < 4; ++sb) {
          f32x4 s = {};
#pragma unroll
          for (int kk = 0; kk < 4; ++kk) {
            int srow = sb * 16 + l15;
            int kb = srow * 256 + (((kk * 4 + l16) ^ (srow & 7)) << 4);
            short8 kf = *(const short8*)((const char*)Ks + kb);
            s = __builtin_amdgcn_mfma_f32_16x16x32_bf16(qf[rf][kk], kf, s, 0, 0, 0);
          }
          S[sb] = s;
        }
        float mx_[4];
        bool grow = false;
#pragma unroll
        for (int r = 0; r < 4; ++r) {
          int tt = wq0 + rf * 16 + 4 * l16 + r;
          float mx = -INFINITY;
#pragma unroll
          for (int sb = 0; sb < 4; ++sb) {
            float v = S[sb][r] * sc;
            if (needmask && (s0 + sb * 16 + l15 > tt)) v = -INFINITY;
            S[sb][r] = v;
            mx = fmaxf(mx, v);
          }
          mx = fmaxf(mx, __shfl_xor(mx, 1));
          mx = fmaxf(mx, __shfl_xor(mx, 2));
          mx = fmaxf(mx, __shfl_xor(mx, 4));
          mx = fmaxf(mx, __shfl_xor(mx, 8));
          mx_[r] = mx;
          grow = grow || (mx > m_r[rf][r] + 8.0f);
        }
        bool anyg = __any(grow);
        float al[4];
#pragma unroll
        for (int r = 0; r < 4; ++r) {
          float mo = m_r[rf][r];
          float mn = mo;
          if (anyg) {
            mn = fmaxf(mo, mx_[r]);
            al[r] = exp2f(mo - mn);
            m_r[rf][r] = mn;
          } else {
            al[r] = 1.0f;
          }
          int prow = rf * 16 + 4 * l16 + r;
          float rs = 0.f;
#pragma unroll
          for (int sb = 0; sb < 4; ++sb) {
            float p = exp2f(S[sb][r] - mn);
            rs += p;
            int pb = (prow * 128 + (sb * 16 + l15) * 2) ^ ((prow & 7) << 4);
            *(u16*)((char*)Ps[wave] + pb) = f2bf(p);
          }
          rs += __shfl_xor(rs, 1);
          rs += __shfl_xor(rs, 2);
          rs += __shfl_xor(rs, 4);
          rs += __shfl_xor(rs, 8);
          l_r[rf][r] = l_r[rf][r] * al[r] + rs;
        }
        if (anyg) {
#pragma unroll
          for (int db = 0; db < 8; ++db)
#pragma unroll
            for (int r = 0; r < 4; ++r) accO[rf][db][r] *= al[r];
        }
        short8 pf[2];
#pragma unroll
        for (int st = 0; st < 2; ++st) {
          int prow = rf * 16 + l15;
          int pb = (prow * 128 + (st * 4 + l16) * 16) ^ ((prow & 7) << 4);
          pf[st] = *(const short8*)((const char*)Ps[wave] + pb);
        }
#pragma unroll
        for (int db = 0; db < 8; ++db) {
#pragma unroll
          for (int st = 0; st < 2; ++st) {
            int vrow = db * 16 + l15;
            int vb = (vrow * 128 + (st * 4 + l16) * 16) ^ ((vrow & 7) << 4);
            short8 vf = *(const short8*)((const char*)Vs + vb);
            accO[rf][db] = __builtin_amdgcn_mfma_f32_16x16x32_bf16(pf[st], vf,
                                                                   accO[rf][db], 0, 0, 0);
          }
        }
      }
    }
    __syncthreads();  // all waves done reading Ks/Vs
    if (more) {
      dswrite();      // compiler inserts vmcnt wait on kreg/vreg here
      __syncthreads();
    }
  }

  int bb = bh >> 4, hh = bh & 15;
#pragma unroll
  for (int rf = 0; rf < 2; ++rf) {
    float inv[4];
#pragma unroll
    for (int r = 0; r < 4; ++r) inv[r] = 1.0f / l_r[rf][r];
#pragma unroll
    for (int db = 0; db < 8; ++db)
#pragma unroll
      for (int r = 0; r < 4; ++r) {
        int tt = wq0 + rf * 16 + 4 * l16 + r;
        o[((long)bb * T_ + tt) * C_ + hh * HD_ + db * 16 + l15] =
            f2bf(accO[rf][db][r] * inv[r]);
      }
  }
}

extern "C" void kernel_launch(void* const* d_in, const int* in_sizes, int n_in,
                              void* d_out, int out_size, void* d_ws, size_t ws_size,
                              hipStream_t stream) {
  (void)in_sizes; (void)n_in; (void)out_size; (void)ws_size;
  const float* x   = (const float*)d_in[0];
  const float* Wq  = (const float*)d_in[1];
  const float* Wk  = (const float*)d_in[2];
  const float* Wv  = (const float*)d_in[3];
  const float* Wp  = (const float*)d_in[4];
  const float* bp  = (const float*)d_in[5];
  const float* W1  = (const float*)d_in[6];
  const float* b1  = (const float*)d_in[7];
  const float* W2  = (const float*)d_in[8];
  const float* b2  = (const float*)d_in[9];
  const float* g1  = (const float*)d_in[10];
  const float* be1 = (const float*)d_in[11];
  const float* g2  = (const float*)d_in[12];
  const float* be2 = (const float*)d_in[13];
  float* out = (float*)d_out;

  char* ws = (char*)d_ws;
  size_t off = 0;
  auto alloc = [&](size_t n) {
    void* p = ws + off;
    off += (n + 255) & ~(size_t)255;
    return p;
  };
  u16* wqkvT = (u16*)alloc((size_t)6144 * 2048 * 2);
  u16* wpT   = (u16*)alloc((size_t)2048 * 2048 * 2);
  u16* w1T   = (u16*)alloc((size_t)8192 * 2048 * 2);
  u16* w2T   = (u16*)alloc((size_t)2048 * 8192 * 2);
  u16* hb    = (u16*)alloc((size_t)8192 * 2048 * 2);
  u16* qbuf  = (u16*)alloc((size_t)8192 * 2048 * 2);
  u16* kbuf  = (u16*)alloc((size_t)8192 * 2048 * 2);
  u16* vtbuf = (u16*)alloc((size_t)8192 * 2048 * 2);
  u16* ob = hb;
  u16* fb = qbuf;

  tconv<<<dim3(64, 4, 16), 256, 0, stream>>>(Wq, wqkvT, 2048, 128,
                                             (long)2048 * 128, (long)128 * 2048);
  tconv<<<dim3(64, 4, 16), 256, 0, stream>>>(Wk, wqkvT + (size_t)2048 * 2048, 2048, 128,
                                             (long)2048 * 128, (long)128 * 2048);
  tconv<<<dim3(64, 4, 16), 256, 0, stream>>>(Wv, wqkvT + (size_t)4096 * 2048, 2048, 128,
                                             (long)2048 * 128, (long)128 * 2048);
  tconv<<<dim3(64, 64, 1), 256, 0, stream>>>(Wp, wpT, 2048, 2048, 0, 0);
  tconv<<<dim3(64, 256, 1), 256, 0, stream>>>(W1, w1T, 2048, 8192, 0, 0);
  tconv<<<dim3(256, 64, 1), 256, 0, stream>>>(W2, w2T, 8192, 2048, 0, 0);

  ln_rows<<<8192, 256, 0, stream>>>(x, g1, be1, hb);
  gemm_bt<0><<<3072, 256, 0, stream>>>(hb, wqkvT, 8192, 6144, 2048, 2048, 2048,
                                       qbuf, kbuf, vtbuf, nullptr, nullptr,
                                       nullptr, nullptr, 0);
  attn_fwd<<<1024, 256, 0, stream>>>(qbuf, kbuf, vtbuf, ob);
  gemm_bt<1><<<1024, 256, 0, stream>>>(ob, wpT, 8192, 2048, 2048, 2048, 2048,
                                       nullptr, nullptr, nullptr, out, x, bp,
                                       nullptr, 0);

  ln_rows<<<8192, 256, 0, stream>>>(out, g2, be2, hb);
  for (int c = 0; c < 4; ++c) {
    gemm_bt<2><<<1024, 256, 0, stream>>>(hb, w1T + (size_t)c * 2048 * 2048,
                                         8192, 2048, 2048, 2048, 2048,
                                         nullptr, nullptr, nullptr, nullptr,
                                         nullptr, b1 + c * 2048, fb, 0);
    gemm_bt<3><<<1024, 256, 0, stream>>>(fb, w2T + (size_t)c * 2048,
                                         8192, 2048, 2048, 2048, 8192,
                                         nullptr, nullptr, nullptr, out,
                                         nullptr, b2, nullptr, c == 0 ? 1 : 0);
  }
}